// Round 7
// baseline (385.797 us; speedup 1.0000x reference)
//
#include <hip/hip_runtime.h>
#include <hip/hip_bf16.h>
#include <math.h>
#include <stdint.h>

#define D_MODEL 1024
#define NHEADS  16
#define NKV     4
#define HD      64
#define SEQ     2048
#define BATCH   4
#define MTOK    (BATCH*SEQ)            // 8192 tokens
#define NQKV    (D_MODEL + 2*NKV*HD)   // 1536
#define ASCALE  0.125f
#define CAP     30.0f

using f32x4  = __attribute__((ext_vector_type(4))) float;
using f32x2  = __attribute__((ext_vector_type(2))) float;
using bf16x8 = __attribute__((ext_vector_type(8))) short;

__device__ __forceinline__ unsigned short f2bf(float f) {
  union { float f; unsigned u; } v; v.f = f;
  unsigned u = v.u + 0x7fffu + ((v.u >> 16) & 1u);
  return (unsigned short)(u >> 16);
}
__device__ __forceinline__ unsigned short f2bf_hup(float f) {  // round-half-up
  union { float f; unsigned u; } v; v.f = f;
  return (unsigned short)((v.u + 0x8000u) >> 16);
}
__device__ __forceinline__ float fexp2(float x) {   // raw v_exp_f32 (arg in [-24,0])
  return __builtin_amdgcn_exp2f(x);
}
__device__ __forceinline__ void async_copy16(void* lds, const void* g) {
  __builtin_amdgcn_global_load_lds(
      (const __attribute__((address_space(1))) unsigned int*)(uintptr_t)g,
      (__attribute__((address_space(3))) unsigned int*)(uintptr_t)lds, 16, 0, 0);
}

// ------- fused fp32->bf16 convert for all 5 inputs + RoPE table build --------
// ropeT[(s*16+ln)] = {cos(s*f0), sin(s*f0), cos(s*f1), sin(s*f1)},
// f0 = 10000^(-ln/32), f1 = f0/100.
__global__ __launch_bounds__(256) void cvt_all(
    const float* __restrict__ x, const float* __restrict__ wq,
    const float* __restrict__ wk, const float* __restrict__ wv,
    const float* __restrict__ wo,
    unsigned short* __restrict__ xb, unsigned short* __restrict__ wqkv,
    unsigned short* __restrict__ wob, float* __restrict__ ropeT) {
  if (blockIdx.x >= 10752) {
    const int tid = (blockIdx.x - 10752) * 256 + threadIdx.x;   // < 32768
    const int s = tid >> 4, ln = tid & 15;
    const float f0 = expf(-(float)ln * 0.28782313662425572f);   // ln(10000)/32
    const float f1 = f0 * 0.01f;
    float4 tb;
    tb.x = cosf((float)s * f0); tb.y = sinf((float)s * f0);
    tb.z = cosf((float)s * f1); tb.w = sinf((float)s * f1);
    *(float4*)(ropeT + (size_t)tid * 4) = tb;
    return;
  }
  const long i = (long)(blockIdx.x * 256 + threadIdx.x) * 4;
  const float* src; unsigned short* dst; long off;
  if (i < 8388608L)      { src = x;  dst = xb;             off = i; }
  else if (i < 9437184L) { src = wq; dst = wqkv;           off = i - 8388608L; }
  else if (i < 9699328L) { src = wk; dst = wqkv + 1048576; off = i - 9437184L; }
  else if (i < 9961472L) { src = wv; dst = wqkv + 1310720; off = i - 9699328L; }
  else                   { src = wo; dst = wob;            off = i - 9961472L; }
  float4 v = *(const float4*)(src + off);
  ushort4 o; o.x = f2bf(v.x); o.y = f2bf(v.y); o.z = f2bf(v.z); o.w = f2bf(v.w);
  *(ushort4*)(dst + off) = o;
}

// ---------------- QKV GEMM + fused RMSNorm/RoPE(table)/repack epilogue -------
// Per-wave 64x64 output quadrant = one head slot. Epilogue routes through a
// per-wave LDS repack tile (stride 72 to break bank alignment) so all global
// stores are coalesced dwordx4.
__global__ __launch_bounds__(256) void gemm_qkv(
    const unsigned short* __restrict__ A, const unsigned short* __restrict__ B,
    const float* __restrict__ qw, const float* __restrict__ kw,
    const float* __restrict__ ropeT,
    unsigned short* __restrict__ Qn, unsigned short* __restrict__ Kn,
    unsigned short* __restrict__ Vt) {
  __shared__ __align__(16) unsigned short As[128 * 32];
  __shared__ __align__(16) unsigned short Bs[128 * 32];
  __shared__ __align__(16) unsigned short Rp[4][64 * 72];
  const int t = threadIdx.x;
  const int w = t >> 6, l = t & 63;
  const int mb = blockIdx.x, nb = blockIdx.y;
  const int wm = w & 1, wn = w >> 1;
  const int quad = l >> 4, ln = l & 15;
  const int K = D_MODEL;
  f32x4 acc[4][4] = {};
  const unsigned short* Ag = A + (size_t)(mb * 128 + w * 32) * K;
  const unsigned short* Bg = B + (size_t)(nb * 128 + w * 32) * K;
  char* Asw = (char*)As + w * 2048;
  char* Bsw = (char*)Bs + w * 2048;
  const int lrow = l >> 2, lcol = (l & 3) * 8;

  for (int kb = 0; kb < K; kb += 32) {
    async_copy16(Asw + l * 16,        Ag + (size_t)lrow * K + kb + lcol);
    async_copy16(Asw + 1024 + l * 16, Ag + (size_t)(16 + lrow) * K + kb + lcol);
    async_copy16(Bsw + l * 16,        Bg + (size_t)lrow * K + kb + lcol);
    async_copy16(Bsw + 1024 + l * 16, Bg + (size_t)(16 + lrow) * K + kb + lcol);
    __syncthreads();
    bf16x8 af[4], bfr[4];
#pragma unroll
    for (int mt = 0; mt < 4; ++mt)
      af[mt] = *(const bf16x8*)(As + (wm * 64 + mt * 16 + ln) * 32 + quad * 8);
#pragma unroll
    for (int nt = 0; nt < 4; ++nt)
      bfr[nt] = *(const bf16x8*)(Bs + (wn * 64 + nt * 16 + ln) * 32 + quad * 8);
#pragma unroll
    for (int mt = 0; mt < 4; ++mt)
#pragma unroll
      for (int nt = 0; nt < 4; ++nt)
        acc[mt][nt] = __builtin_amdgcn_mfma_f32_16x16x32_bf16(af[mt], bfr[nt], acc[mt][nt], 0, 0, 0);
    __syncthreads();
  }

  const int hs = nb * 2 + wn;                    // head slot 0..23
  const int bB = mb >> 4;
  const int sBase = ((mb & 15) * 128) + wm * 64;
  unsigned short* rp = Rp[w];

  if (hs < 20) {
    const float* wgt = (hs < 16) ? qw : kw;
    float wv_[4];
#pragma unroll
    for (int nt = 0; nt < 4; ++nt) wv_[nt] = wgt[nt * 16 + ln];
    unsigned short* dst = (hs < 16)
        ? Qn + (size_t)(bB * 16 + hs) * SEQ * 64
        : Kn + (size_t)(bB * 4 + (hs - 16)) * SEQ * 64;
#pragma unroll
    for (int mt = 0; mt < 4; ++mt) {
#pragma unroll
      for (int r = 0; r < 4; ++r) {
        const int rowL = mt * 16 + quad * 4 + r;
        const int sTok = sBase + rowL;
        float ss = 0.f;
#pragma unroll
        for (int nt = 0; nt < 4; ++nt) ss = fmaf(acc[mt][nt][r], acc[mt][nt][r], ss);
        ss += __shfl_xor(ss, 1, 64); ss += __shfl_xor(ss, 2, 64);
        ss += __shfl_xor(ss, 4, 64); ss += __shfl_xor(ss, 8, 64);
        const float inv = rsqrtf(ss * (1.0f / 64.0f) + 1e-6f);
        float xn[4];
#pragma unroll
        for (int nt = 0; nt < 4; ++nt) xn[nt] = acc[mt][nt][r] * inv * wv_[nt];
        const float4 tb = *(const float4*)(ropeT + ((size_t)sTok * 16 + ln) * 4);
        rp[rowL * 72 + ln]      = f2bf(xn[0] * tb.x - xn[2] * tb.y);
        rp[rowL * 72 + ln + 16] = f2bf(xn[1] * tb.z - xn[3] * tb.w);
        rp[rowL * 72 + ln + 32] = f2bf(xn[2] * tb.x + xn[0] * tb.y);
        rp[rowL * 72 + ln + 48] = f2bf(xn[3] * tb.z + xn[1] * tb.w);
      }
    }
    __builtin_amdgcn_s_waitcnt(0xc07f);   // lgkmcnt(0): wave-private repack
#pragma unroll
    for (int i = 0; i < 8; ++i) {
      const int row = (l >> 3) + i * 8, c8 = l & 7;
      bf16x8 v = *(const bf16x8*)(rp + row * 72 + c8 * 8);
      *(bf16x8*)(dst + (size_t)(sBase + row) * 64 + c8 * 8) = v;
    }
  } else {
    unsigned short* dst = Vt + (size_t)(bB * 4 + (hs - 20)) * 64 * SEQ;
#pragma unroll
    for (int mt = 0; mt < 4; ++mt)
#pragma unroll
      for (int nt = 0; nt < 4; ++nt)
#pragma unroll
        for (int r = 0; r < 4; ++r)
          rp[(nt * 16 + ln) * 72 + mt * 16 + quad * 4 + r] = f2bf(acc[mt][nt][r]);
    __builtin_amdgcn_s_waitcnt(0xc07f);
#pragma unroll
    for (int i = 0; i < 8; ++i) {
      const int d = (l >> 3) + i * 8, c8 = l & 7;
      bf16x8 v = *(const bf16x8*)(rp + d * 72 + c8 * 8);
      *(bf16x8*)(dst + (size_t)d * SEQ + sBase + c8 * 8) = v;
    }
  }
}

// ---------------- GEMM: C[M,N] f32 = A[M,K]bf16 * B[N,K]bf16^T ----------------
__global__ __launch_bounds__(256) void gemm_bt_f32(
    const unsigned short* __restrict__ A, const unsigned short* __restrict__ B,
    float* __restrict__ C, int M, int N, int K) {
  __shared__ __align__(16) unsigned short As[128 * 32];
  __shared__ __align__(16) unsigned short Bs[128 * 32];
  const int t = threadIdx.x;
  const int w = t >> 6, l = t & 63;
  const int mb = blockIdx.x, nb = blockIdx.y;
  const int wm = w & 1, wn = w >> 1;
  f32x4 acc[4][4] = {};
  const unsigned short* Ag = A + (size_t)(mb * 128 + w * 32) * K;
  const unsigned short* Bg = B + (size_t)(nb * 128 + w * 32) * K;
  char* Asw = (char*)As + w * 2048;
  char* Bsw = (char*)Bs + w * 2048;
  const int lrow = l >> 2, lcol = (l & 3) * 8;

  for (int kb = 0; kb < K; kb += 32) {
    async_copy16(Asw + l * 16,        Ag + (size_t)lrow * K + kb + lcol);
    async_copy16(Asw + 1024 + l * 16, Ag + (size_t)(16 + lrow) * K + kb + lcol);
    async_copy16(Bsw + l * 16,        Bg + (size_t)lrow * K + kb + lcol);
    async_copy16(Bsw + 1024 + l * 16, Bg + (size_t)(16 + lrow) * K + kb + lcol);
    __syncthreads();
    bf16x8 af[4], bfr[4];
#pragma unroll
    for (int mt = 0; mt < 4; ++mt)
      af[mt] = *(const bf16x8*)(As + (wm * 64 + mt * 16 + (l & 15)) * 32 + (l >> 4) * 8);
#pragma unroll
    for (int nt = 0; nt < 4; ++nt)
      bfr[nt] = *(const bf16x8*)(Bs + (wn * 64 + nt * 16 + (l & 15)) * 32 + (l >> 4) * 8);
#pragma unroll
    for (int mt = 0; mt < 4; ++mt)
#pragma unroll
      for (int nt = 0; nt < 4; ++nt)
        acc[mt][nt] = __builtin_amdgcn_mfma_f32_16x16x32_bf16(af[mt], bfr[nt], acc[mt][nt], 0, 0, 0);
    __syncthreads();
  }
  const int row0 = mb * 128 + wm * 64, col0 = nb * 128 + wn * 64;
#pragma unroll
  for (int mt = 0; mt < 4; ++mt)
#pragma unroll
    for (int nt = 0; nt < 4; ++nt)
#pragma unroll
      for (int r = 0; r < 4; ++r) {
        int row = row0 + mt * 16 + (l >> 4) * 4 + r;
        int col = col0 + nt * 16 + (l & 15);
        C[(size_t)row * N + col] = acc[mt][nt][r];
      }
}

// ---------------- flash attention: barrier-free, direct-global K/V frags -----
// 128q block, 4 waves x 32q. K and V^T MFMA B-fragments are contiguous 16B
// global spans -> global_load_dwordx4 straight to VGPRs; no LDS staging, no
// __syncthreads. 4 waves re-read the same 8KB tile through L1. Only the P
// C-layout -> A-layout transform round-trips through wave-private LDS.
__global__ __launch_bounds__(256, 4) void attn(
    const unsigned short* __restrict__ Qn, const unsigned short* __restrict__ Kn,
    const unsigned short* __restrict__ Vtg, unsigned short* __restrict__ O) {
  __shared__ __align__(16) unsigned short Ps[8192];   // 4 waves x 32q x 64kv
  const int t = threadIdx.x, w = t >> 6, l = t & 63;
  const int quad = l >> 4, ln = l & 15;
  const int bid = blockIdx.x;
  const int qt = 15 - (bid >> 6);                     // LPT schedule
  const int bh = bid & 63;
  const int h = bh & 15, b = bh >> 4;
  const int q0 = qt * 128;
  const int wq0 = q0 + w * 32;
  const unsigned short* Qh = Qn + ((size_t)(b * 16 + h)) * SEQ * 64;
  const unsigned short* Kg = Kn + ((size_t)(b * 4 + (h >> 2))) * SEQ * 64;
  const unsigned short* Vg = Vtg + ((size_t)(b * 4 + (h >> 2))) * 64 * SEQ;

  bf16x8 aq[2][2];
#pragma unroll
  for (int mt = 0; mt < 2; ++mt)
#pragma unroll
    for (int ks = 0; ks < 2; ++ks)
      aq[mt][ks] = *(const bf16x8*)(Qh + (size_t)(wq0 + mt * 16 + ln) * 64 + ks * 32 + quad * 8);
  f32x4 o_acc[2][4] = {};
  f32x2 lp[2][2] = {};

  const float Cc = 0.18033688011112042f;   // ASCALE * log2(e)
  const float B1 = -5.787037037e-6f;       // -(ASCALE/CAP)^2 / 3
  const float M2 = 11.541560327f;          // 8 * log2(e)

  const int jmaxw = ((wq0 + 31) >> 6) + 1;            // per-wave, ragged
  for (int jj = 0; jj < jmaxw; ++jj) {
    const int kv0 = jj * 64;

    // K fragments straight from global (16B/lane each)
    bf16x8 bk[4][2];
#pragma unroll
    for (int nt = 0; nt < 4; ++nt)
#pragma unroll
      for (int ks = 0; ks < 2; ++ks)
        bk[nt][ks] = *(const bf16x8*)(Kg + (size_t)(kv0 + nt * 16 + ln) * 64 + ks * 32 + quad * 8);

    // S = Q K^T
    f32x4 sacc[2][4] = {};
#pragma unroll
    for (int nt = 0; nt < 4; ++nt)
#pragma unroll
      for (int ks = 0; ks < 2; ++ks) {
        sacc[0][nt] = __builtin_amdgcn_mfma_f32_16x16x32_bf16(aq[0][ks], bk[nt][ks], sacc[0][nt], 0, 0, 0);
        sacc[1][nt] = __builtin_amdgcn_mfma_f32_16x16x32_bf16(aq[1][ks], bk[nt][ks], sacc[1][nt], 0, 0, 0);
      }

    // V fragments issue now; latency hidden behind softmax
    bf16x8 bv[4][2];
#pragma unroll
    for (int nt = 0; nt < 4; ++nt)
#pragma unroll
      for (int ks = 0; ks < 2; ++ks)
        bv[nt][ks] = *(const bf16x8*)(Vg + (size_t)(nt * 16 + ln) * SEQ + kv0 + ks * 32 + quad * 8);

    const bool needMask = (kv0 + 63 > wq0);
#pragma unroll
    for (int mt = 0; mt < 2; ++mt)
#pragma unroll
      for (int nt = 0; nt < 4; ++nt) {
        const int col = nt * 16 + ln;
        const int base = w * 2048 + mt * 1024 + (col >> 5) * 512 +
                         ((((col >> 3) & 3) ^ quad) << 3) + (col & 7);
#pragma unroll
        for (int rp = 0; rp < 2; ++rp) {
          f32x2 s = { sacc[mt][nt][rp * 2], sacc[mt][nt][rp * 2 + 1] };
          f32x2 s2 = s * s;
          f32x2 tt = s2 * B1 + 1.0f;
          f32x2 arg = (s * Cc) * tt - M2;
          float pr0 = fexp2(arg.x), pr1 = fexp2(arg.y);
          if (needMask) {
            const int qrow = wq0 + mt * 16 + quad * 4 + rp * 2;
            if ((kv0 + col) > qrow)     pr0 = 0.0f;
            if ((kv0 + col) > qrow + 1) pr1 = 0.0f;
          }
          lp[mt][rp] += (f32x2){pr0, pr1};
          Ps[base + (quad * 4 + rp * 2) * 32]     = f2bf_hup(pr0);
          Ps[base + (quad * 4 + rp * 2 + 1) * 32] = f2bf_hup(pr1);
        }
      }
    __builtin_amdgcn_s_waitcnt(0xc07f);   // lgkmcnt(0): own-wave P writes -> reads

    // O += P V
    bf16x8 ap[2][2];
#pragma unroll
    for (int mt = 0; mt < 2; ++mt)
#pragma unroll
      for (int ks = 0; ks < 2; ++ks)
        ap[mt][ks] = *(const bf16x8*)((char*)Ps + w * 4096 + mt * 2048 + ks * 1024 +
                                      ln * 64 + ((quad ^ (ln >> 2)) << 4));
#pragma unroll
    for (int nt = 0; nt < 4; ++nt)
#pragma unroll
      for (int ks = 0; ks < 2; ++ks) {
        o_acc[0][nt] = __builtin_amdgcn_mfma_f32_16x16x32_bf16(ap[0][ks], bv[nt][ks], o_acc[0][nt], 0, 0, 0);
        o_acc[1][nt] = __builtin_amdgcn_mfma_f32_16x16x32_bf16(ap[1][ks], bv[nt][ks], o_acc[1][nt], 0, 0, 0);
      }
  }

  // epilogue
  float invl[2][4];
#pragma unroll
  for (int mt = 0; mt < 2; ++mt)
#pragma unroll
    for (int r = 0; r < 4; ++r) {
      float s = lp[mt][r >> 1][r & 1];
      s += __shfl_xor(s, 1, 64); s += __shfl_xor(s, 2, 64);
      s += __shfl_xor(s, 4, 64); s += __shfl_xor(s, 8, 64);
      invl[mt][r] = __builtin_amdgcn_rcpf(s);
    }
#pragma unroll
  for (int mt = 0; mt < 2; ++mt)
#pragma unroll
    for (int nt = 0; nt < 4; ++nt)
#pragma unroll
      for (int r = 0; r < 4; ++r) {
        int qrow = wq0 + mt * 16 + quad * 4 + r;
        int col = h * 64 + nt * 16 + ln;
        O[((size_t)(b * SEQ + qrow)) * 1024 + col] = f2bf_hup(o_acc[mt][nt][r] * invl[mt][r]);
      }
}

// ---------------- launch ----------------
extern "C" void kernel_launch(void* const* d_in, const int* in_sizes, int n_in,
                              void* d_out, int out_size, void* d_ws, size_t ws_size,
                              hipStream_t stream) {
  const float* x  = (const float*)d_in[0];
  const float* Wq = (const float*)d_in[1];
  const float* Wk = (const float*)d_in[2];
  const float* Wv = (const float*)d_in[3];
  const float* Wo = (const float*)d_in[4];
  const float* qw = (const float*)d_in[5];
  const float* kw = (const float*)d_in[6];
  float* out = (float*)d_out;

  char* ws = (char*)d_ws;
  unsigned short* xb   = (unsigned short*)(ws);                 // 16,777,216
  unsigned short* wqkv = (unsigned short*)(ws + 16777216);      //  3,145,728
  unsigned short* wo   = (unsigned short*)(ws + 19922944);      //  2,097,152
  unsigned short* Qn   = (unsigned short*)(ws + 22020096);      // 16,777,216
  unsigned short* Kn   = (unsigned short*)(ws + 38797312);      //  4,194,304
  unsigned short* Vtg  = (unsigned short*)(ws + 42991616);      //  4,194,304
  unsigned short* Ob   = (unsigned short*)(ws + 47185920);      // 16,777,216
  float*          ropeT= (float*)         (ws + 63963136);      //     524,288  -> ~64.5 MB

  cvt_all<<<10880, 256, 0, stream>>>(x, Wq, Wk, Wv, Wo, xb, wqkv, wo, ropeT);
  gemm_qkv<<<dim3(MTOK / 128, NQKV / 128), 256, 0, stream>>>(xb, wqkv, qw, kw, ropeT, Qn, Kn, Vtg);
  attn<<<1024, 256, 0, stream>>>(Qn, Kn, Vtg, Ob);
  gemm_bt_f32<<<dim3(MTOK / 128, 1024 / 128), 256, 0, stream>>>(Ob, wo, out, MTOK, 1024, 1024);
}